// Round 9
// baseline (148.456 us; speedup 1.0000x reference)
//
#include <hip/hip_runtime.h>
#include <hip/hip_bf16.h>
#include <math.h>

typedef __attribute__((ext_vector_type(8))) short bf16x8;
typedef __attribute__((ext_vector_type(4))) float f32x4;

#define SEQ 1024
#define DIM 768
#define NH 12
#define HD 64

// ws layout (BYTE offsets):
//   Qb   bf16 [12][1024][64]  @ 0
//   Kb   bf16 [12][1024][64]  @ 1572864
//   Vt   bf16 [768][1024]     @ 3145728   (v transposed: [h*64+e][l])
//   opre bf16 [1024][768]     @ 4718592
//   G    f32  [1024][36]      @ 6291456
//   si   f32  [12][1024]      @ 6438912
//   Xb   bf16 [1024][768]     @ 6684672   (pre-cast inputs for DMA staging)
//   Wqb  bf16 [768][768]      @ 8257536
//   Wkb  bf16 [768][768]      @ 9437184
//   Wvb  bf16 [768][768]      @ 10616832
//   (Wub slot unused since R19)
//   Wgb  bf16 [36][768]       @ 12976128
//   Wob  bf16 [768][768]      @ 13031424
// u (bf16 [12][1024][64]) borrows d_out as scratch; k_oproj overwrites it last.
// NOTE (R9): grid.sync() costs ~50 µs on MI355X — never fuse via cooperative.
// R12/R14: two failed scan merges. LESSON: latency-bound lever = (serial
// iters/wave) x concurrency; never buy a launch boundary with serialization.
// The ONLY merge type that works: grid CONCATENATION of independent blocks.
// R13: f32 reg-staging costs +10 µs vs bf16-precast DMA (whole proj5).
// R15: k_si j-split across waves (768 blocks, <=16 serial iters/wave). -9 µs.
// R16: proj5 64x64 re-tile, 784 blocks. R17: scan folded into attn. 144.5 µs.
// Budget: kernel work ~35 µs + ~10 µs/boundary + ~43 µs harness ws-fill.
// R19: 5->4 kernels. (a) u-GEMM moved into k_prep as grid segment (reads f32
// X/Wu reg-staged — in-register bf16 cast is bitwise-identical to old path;
// f32-staging penalty only on this 1/5 of proj work). (b) k_si concatenated
// into k_proj5's grid (si blocks read Ub produced by PREVIOUS kernel — pure
// block union, zero added serialization).

__device__ __forceinline__ float wave_reduce_sum(float v) {
    for (int off = 1; off < 64; off <<= 1) v += __shfl_xor(v, off);
    return v;
}
__device__ __forceinline__ short f2bs(float x) {
    __hip_bfloat16 h = __float2bfloat16(x);
    return *reinterpret_cast<short*>(&h);
}
__device__ __forceinline__ float bs2f(short x) {
    __hip_bfloat16 h = *reinterpret_cast<__hip_bfloat16*>(&x);
    return (float)h;
}
__device__ __forceinline__ bf16x8 cvt8r(const float4& a, const float4& b) {
    bf16x8 r;
    r[0]=f2bs(a.x); r[1]=f2bs(a.y); r[2]=f2bs(a.z); r[3]=f2bs(a.w);
    r[4]=f2bs(b.x); r[5]=f2bs(b.y); r[6]=f2bs(b.z); r[7]=f2bs(b.w);
    return r;
}
__device__ __forceinline__ void async_copy16(const void* gptr, void* ldsbase, int lane) {
#if __has_builtin(__builtin_amdgcn_global_load_lds)
    __builtin_amdgcn_global_load_lds(
        (const __attribute__((address_space(1))) unsigned int*)gptr,
        (__attribute__((address_space(3))) unsigned int*)ldsbase, 16, 0, 0);
#else
    *(bf16x8*)((short*)ldsbase + lane*8) = *(const bf16x8*)gptr;
#endif
}

// ---------------- K0: pre-cast to bf16 (segs 0-5) + u-GEMM (seg 6) ----------
// seg 6: u = X @ Wu^T from f32 sources, 64x64 reg-staged T14 dbuf GEMM,
// 192 blocks (rt 0..15 x head ct 0..11). Writes Ub[ct][l][e] (d_out scratch).
__global__ __launch_bounds__(256, 3) void k_prep(const float* __restrict__ X,
    const float* __restrict__ Wq, const float* __restrict__ Wk,
    const float* __restrict__ Wv, const float* __restrict__ Wg,
    const float* __restrict__ Wo, const float* __restrict__ Wu,
    short* __restrict__ Xb, short* __restrict__ Wqb, short* __restrict__ Wkb,
    short* __restrict__ Wvb, short* __restrict__ Wgb, short* __restrict__ Wob,
    __hip_bfloat16* __restrict__ Ub)
{
    int seg = blockIdx.y;
    __shared__ short lds[16384];   // u-GEMM: A dbuf @0/4096, B dbuf @8192/12288

    if (seg == 6) {
        int x = blockIdx.x;
        if (x >= 192) return;
        int rt = x / 12, ct = x % 12;
        int tid = threadIdx.x;
        int wv = tid>>6, lane = tid&63, g = lane>>4, n = lane&15;
        int wm = wv>>1, wn = wv&1;

        float4 ra[2][2], rb[2][2];
        auto load_step = [&](int k0) {
#pragma unroll
            for (int p = 0; p < 2; ++p) {
                int s = p*256 + wv*64 + lane;
                int r = s >> 3, c = s & 7, cl = c ^ (r & 7);
                const float* ap = X  + (size_t)(rt*64 + r)*DIM + k0 + cl*8;
                ra[p][0] = *(const float4*)ap; ra[p][1] = *(const float4*)(ap + 4);
                const float* bp = Wu + (size_t)(ct*64 + r)*DIM + k0 + cl*8;
                rb[p][0] = *(const float4*)bp; rb[p][1] = *(const float4*)(bp + 4);
            }
        };
        auto write_step = [&](int buf) {
            short* Ab = lds + buf*4096;
            short* Bb = lds + 8192 + buf*4096;
#pragma unroll
            for (int p = 0; p < 2; ++p) {
                int s = p*256 + wv*64 + lane;
                *(bf16x8*)(Ab + s*8) = cvt8r(ra[p][0], ra[p][1]);
                *(bf16x8*)(Bb + s*8) = cvt8r(rb[p][0], rb[p][1]);
            }
        };

        f32x4 acc[2][2];
        for (int i=0;i<2;++i) for (int j=0;j<2;++j) acc[i][j] = (f32x4){0,0,0,0};

        load_step(0); write_step(0);
        for (int it = 0; it < 12; ++it) {
            __syncthreads();
            if (it < 11) load_step((it + 1)*64);
            int buf = it & 1;
            const short* Ab = lds + buf*4096;
            const short* Bb = lds + 8192 + buf*4096;
            for (int ks = 0; ks < 2; ++ks) {
                int q = ks*4 + g;
                bf16x8 af[2], bfr[2];
                for (int i=0;i<2;++i)
                    af[i] = *(const bf16x8*)(&Ab[((wm*32+i*16+n)*8 + (q ^ (n&7)))*8]);
                for (int j=0;j<2;++j)
                    bfr[j] = *(const bf16x8*)(&Bb[((wn*32+j*16+n)*8 + (q ^ (n&7)))*8]);
                for (int i=0;i<2;++i)
                    for (int j=0;j<2;++j)
                        acc[i][j] = __builtin_amdgcn_mfma_f32_16x16x32_bf16(af[i], bfr[j], acc[i][j], 0,0,0);
            }
            if (it < 11) write_step(1 - (it & 1));   // cvt+write after MFMA (T14)
        }
        for (int i=0;i<2;++i) for (int j=0;j<2;++j) for (int r=0;r<4;++r) {
            int row = wm*32 + i*16 + g*4 + r;
            int col = wn*32 + j*16 + n;
            Ub[((size_t)ct*SEQ + rt*64 + row)*HD + col] = __float2bfloat16(acc[i][j][r]);
        }
        return;
    }

    const float* src; short* dst; int n8;
    switch (seg) {
        case 0: src = X;  dst = Xb;  n8 = 98304; break;
        case 1: src = Wq; dst = Wqb; n8 = 73728; break;
        case 2: src = Wk; dst = Wkb; n8 = 73728; break;
        case 3: src = Wv; dst = Wvb; n8 = 73728; break;
        case 4: src = Wg; dst = Wgb; n8 = 3456;  break;
        default: src = Wo; dst = Wob; n8 = 73728; break;
    }
    int i = blockIdx.x*256 + threadIdx.x;
    if (i >= n8) return;
    const float* s = src + (size_t)i*8;
    *(bf16x8*)(dst + (size_t)i*8) = cvt8r(*(const float4*)s, *(const float4*)(s + 4));
}

// ---------------- K1: q/k/v/gate projections + si, 1360 blocks --------------
// t < 192: q; < 384: k; < 576: v (A/B swapped); < 592: gate; >= 592: si
// (768 blocks, h = idx/64, T = idx%64 — R15 body, reads Ub from k_prep).
__global__ __launch_bounds__(256, 4) void k_projsi(const short* __restrict__ Xb,
    const short* __restrict__ Wqb, const short* __restrict__ Wkb,
    const short* __restrict__ Wvb, const short* __restrict__ Wgb,
    const __hip_bfloat16* __restrict__ Ub, const float* __restrict__ pmu,
    const float* __restrict__ plt,
    __hip_bfloat16* __restrict__ Qb, __hip_bfloat16* __restrict__ Kb,
    __hip_bfloat16* __restrict__ Vt, float* __restrict__ G,
    float* __restrict__ si_)
{
    int t = blockIdx.x;
    __shared__ short lds[16384];   // proj: A dbuf @0/4096, B dbuf @8192/12288
    int tid = threadIdx.x;
    int wv = tid>>6, lane = tid&63, g = lane>>4, n = lane&15;

    if (t >= 592) {
        // ---- si body (R15): MFMA causal Gram rowsum, j-split across waves --
        int idx = t - 592;
        int h = idx >> 6, T = idx & 63;
        float* pbuf = (float*)lds;            // [4][16]
        int lbase = T*16;
        const short* ub = (const short*)Ub + (size_t)h*SEQ*HD;

        bf16x8 a0 = *(const bf16x8*)(ub + (size_t)(lbase + n)*HD + g*8);
        bf16x8 a1 = *(const bf16x8*)(ub + (size_t)(lbase + n)*HD + 32 + g*8);

        float p[4] = {0.f, 0.f, 0.f, 0.f};
        for (int jt = wv; jt < T; jt += 4) {  // strictly-below tiles: unmasked
            const short* br = ub + (size_t)(jt*16 + n)*HD + g*8;
            bf16x8 b0 = *(const bf16x8*)br;
            bf16x8 b1 = *(const bf16x8*)(br + 32);
            f32x4 sacc = {0.f,0.f,0.f,0.f};
            sacc = __builtin_amdgcn_mfma_f32_16x16x32_bf16(a0, b0, sacc, 0,0,0);
            sacc = __builtin_amdgcn_mfma_f32_16x16x32_bf16(a1, b1, sacc, 0,0,0);
            for (int r = 0; r < 4; ++r) p[r] += sacc[r];
        }
        if (wv == 0) {                        // diagonal tile: mask j<=l
            const short* br = ub + (size_t)(lbase + n)*HD + g*8;
            bf16x8 b0 = *(const bf16x8*)br;
            bf16x8 b1 = *(const bf16x8*)(br + 32);
            f32x4 d = {0.f,0.f,0.f,0.f};
            d = __builtin_amdgcn_mfma_f32_16x16x32_bf16(a0, b0, d, 0,0,0);
            d = __builtin_amdgcn_mfma_f32_16x16x32_bf16(a1, b1, d, 0,0,0);
            for (int r = 0; r < 4; ++r) if (n <= g*4 + r) p[r] += d[r];
        }
        if (wv == 1) {                        // prior-mu term
            float ltau = expf(fminf(fmaxf(plt[h], -50.f), 30.f));
            for (int r = 0; r < 4; ++r) {
                int l = lbase + g*4 + r;
                float acc = 0.f;
                for (int c = n; c < 64; c += 16)
                    acc += bs2f(ub[(size_t)l*HD + c]) * pmu[h*HD + c];
                p[r] += ltau * acc;
            }
        }
        for (int off = 1; off < 16; off <<= 1)
            for (int r = 0; r < 4; ++r) p[r] += __shfl_xor(p[r], off);
        if (n == 0)
            for (int r = 0; r < 4; ++r) pbuf[wv*16 + g*4 + r] = p[r];
        __syncthreads();
        if (wv == 0 && n == 0) {
            float ltau = expf(fminf(fmaxf(plt[h], -50.f), 30.f));
            for (int r = 0; r < 4; ++r) {
                int row = g*4 + r, l = lbase + row;
                float tot = pbuf[row] + pbuf[16 + row] + pbuf[32 + row] + pbuf[48 + row];
                si_[h*SEQ + l] = -tot * 0.125f / (ltau + (float)(l + 1));
            }
        }
        return;
    }

    // ---- projection body (R16 64x64 4-wave) ----
    int mat, rt, ct;
    if (t < 384)      { mat = t/192; int r = t%192; rt = r/12; ct = r%12; }   // q,k
    else if (t < 576) { mat = 2; int r = t-384; rt = r/16; ct = r%16; }       // v
    else              { mat = 4; rt = t-576; ct = 0; }                        // gate

    int wm = wv>>1, wn = wv&1;

    const short* Asrc; const short* Bsrc; int arow0, brow0, Brows;
    if (mat == 2) { Asrc = Wvb; Bsrc = Xb; arow0 = rt*64; brow0 = ct*64; Brows = SEQ; }
    else {
        Asrc = Xb; arow0 = rt*64; brow0 = ct*64;
        Bsrc = (mat==0)?Wqb:(mat==1)?Wkb:Wgb;
        Brows = (mat==4) ? 36 : DIM;
    }

    auto dma_step = [&](int buf, int k0) {
        short* Ab = lds + buf*4096;
        short* Bb = lds + 8192 + buf*4096;
        for (int p = 0; p < 2; ++p) {
            int sbase = p*256 + wv*64;
            int s = sbase + lane;
            int r = s >> 3, c = s & 7, cl = c ^ (r & 7);
            async_copy16(Asrc + (size_t)(arow0 + r)*DIM + k0 + cl*8, Ab + sbase*8, lane);
            int gr = brow0 + r; if (gr >= Brows) gr = Brows - 1;   // gate clamp
            async_copy16(Bsrc + (size_t)gr*DIM + k0 + cl*8, Bb + sbase*8, lane);
        }
    };

    f32x4 acc[2][2];
    for (int i=0;i<2;++i) for (int j=0;j<2;++j) acc[i][j] = (f32x4){0,0,0,0};

    dma_step(0, 0);
    for (int it = 0; it < 12; ++it) {
        __syncthreads();                                // drains DMA for buf it&1
        if (it < 11) dma_step(1 - (it & 1), (it + 1)*64);
        int buf = it & 1;
        const short* Ab = lds + buf*4096;
        const short* Bb = lds + 8192 + buf*4096;
        for (int ks = 0; ks < 2; ++ks) {
            int q = ks*4 + g;
            bf16x8 af[2], bfr[2];
            for (int i=0;i<2;++i)
                af[i] = *(const bf16x8*)(&Ab[((wm*32+i*16+n)*8 + (q ^ (n&7)))*8]);
            for (int j=0;j<2;++j)
                bfr[j] = *(const bf16x8*)(&Bb[((wn*32+j*16+n)*8 + (q ^ (n&7)))*8]);
            for (int i=0;i<2;++i)
                for (int j=0;j<2;++j)
                    acc[i][j] = __builtin_amdgcn_mfma_f32_16x16x32_bf16(af[i], bfr[j], acc[i][j], 0,0,0);
        }
    }
    __syncthreads();

    // ---- gate: tiny, direct f32 writes (cols >= 36 masked) ----
    if (mat == 4) {
        for (int i=0;i<2;++i) for (int j=0;j<2;++j) for (int r=0;r<4;++r) {
            int row = rt*64 + wm*32 + i*16 + g*4 + r;
            int col = wn*32 + j*16 + n;
            if (col < 36) G[(size_t)row*36 + col] = acc[i][j][r];
        }
        return;
    }

    // ---- stage C tile bf16 [64 rows][64 cols] in LDS (reuses A0 buffer) ----
    short* C = lds;
    for (int i=0;i<2;++i) for (int j=0;j<2;++j) for (int r=0;r<4;++r)
        C[(wm*32 + i*16 + g*4 + r)*64 + wn*32 + j*16 + n] = f2bs(acc[i][j][r]);
    __syncthreads();

    if (mat == 2) {
        // C[e_local][l_local] -> Vt[rt*64+e][ct*64+l], 128B runs via uint
        const unsigned int* Cu = (const unsigned int*)C;
        for (int k = 0; k < 8; ++k) {
            int idx = k*256 + tid;           // 0..2047
            int row = idx >> 5, cu = idx & 31;
            ((unsigned int*)(Vt + (size_t)(rt*64 + row)*SEQ + ct*64))[cu] = Cu[row*32 + cu];
        }
    } else {
        // q/k: fused RoPE (rotation recurrence) + L2 normalize, head = ct.
        __hip_bfloat16* dst = (mat==0) ? Qb : Kb;
        int i2 = lane >> 1;
        float inv = expf((float)i2 * (-9.210340371976184f / 32.f));  // 10000^{-i2/32}
        float c0, s0, C1, S1;
        sincosf((float)(rt*64 + wv*16) * inv, &s0, &c0);
        sincosf(inv, &S1, &C1);
        for (int k = 0; k < 16; ++k) {
            int row = wv*16 + k;
            int l = rt*64 + row;
            float x = bs2f(C[row*64 + lane]);
            float p = __shfl(x, lane ^ 32);
            float rot = (lane < 32) ? -p : p;
            float y = x*c0 + rot*s0;
            float nrm = wave_reduce_sum(y*y);
            y = y / fmaxf(sqrtf(nrm), 1e-12f);
            dst[((size_t)ct*SEQ + l)*HD + lane] = __float2bfloat16(y);
            float cn = c0*C1 - s0*S1;
            s0 = s0*C1 + c0*S1;
            c0 = cn;
        }
    }
}

// ---------------- K4: attn + inline per-block scan + LayerNorm ---------------
// R17: alpha/beta/gamma computed in-block from si with a BLOCK-LOCAL max.
__global__ __launch_bounds__(256) void k_attn(const __hip_bfloat16* __restrict__ Qb,
    const __hip_bfloat16* __restrict__ Kb, const __hip_bfloat16* __restrict__ Vt,
    const float* __restrict__ si_, const float* __restrict__ Gm,
    __hip_bfloat16* __restrict__ opre)
{
    int t = blockIdx.x, h = blockIdx.y;   // q-tile 0..63
    int tid = threadIdx.x;
    int wv = tid >> 6, lane = tid & 63;
    int g = lane >> 4, n = lane & 15;
    __shared__ short P[4][16*64];
    __shared__ float Op[4][16][64];
    __shared__ float red[4][2];
    __shared__ float ABG[3][16];
    __shared__ float smax_s;
    short* Pw = P[wv];
    int m0 = t*16;
    const float* si = si_ + h*SEQ;

    const short* qrow = (const short*)Qb + ((size_t)h*SEQ + m0 + n)*HD + g*8;
    bf16x8 qa0 = *(const bf16x8*)qrow;
    bf16x8 qa1 = *(const bf16x8*)(qrow + 32);

    // Phase A: block-local max over si[0 .. m0+16)
    float mx = -1e30f;
    for (int j = tid; j < m0 + 16; j += 256) mx = fmaxf(mx, si[j]);
    for (int off = 1; off < 64; off <<= 1) mx = fmaxf(mx, __shfl_xor(mx, off));
    if (lane == 0) red[wv][0] = mx;
    __syncthreads();
    if (tid == 0) smax_s = fmaxf(fmaxf(red[0][0], red[1][0]), fmaxf(red[2][0], red[3][0]));
    __syncthreads();
    float sm = smax_s;

    // Phase B: E_base/P_base = sums over j < m0
    float se = 0.f, ss = 0.f;
    for (int j = tid; j < m0; j += 256) { float s = si[j]; se += expf(s - sm); ss += s; }
    se = wave_reduce_sum(se); ss = wave_reduce_sum(ss);
    __syncthreads();                       // red[][] reuse
    if (lane == 0) { red[wv][0] = se; red[wv][1] = ss; }
    __syncthreads();

    // Phase C: wave 0 lanes 0..15 -> per-row alpha/beta/gamma
    if (wv == 0 && lane < 16) {
        float Eb = red[0][0] + red[1][0] + red[2][0] + red[3][0];
        float Pb = red[0][1] + red[1][1] + red[2][1] + red[3][1];
        float sv = si[m0 + lane];
        float pe = expf(sv - sm), ps = sv;
        for (int off = 1; off < 16; off <<= 1) {
            float t1 = __shfl_up(pe, off), t2 = __shfl_up(ps, off);
            if (lane >= off) { pe += t1; ps += t2; }
        }
        float E = Eb + pe, Pv = Pb + ps;   // inclusive prefixes at row m0+lane
        float tv = (float)(m0 + lane + 1);
        float s1 = 1.f / (1.f + expf(-Gm[(size_t)(m0 + lane)*36 + h*3 + 0]));
        float sh = 1.f / (1.f + expf(-Gm[(size_t)(m0 + lane)*36 + h*3 + 1]));
        float a = sh / (E + 1e-12f);
        float b = (s1 - sh) / tv;
        ABG[0][lane] = a;
        ABG[1][lane] = b;
        ABG[2][lane] = -((b * Pv + sh) / tv);
    }
    __syncthreads();

    float A_[4], B_[4], G_[4];
    for (int r = 0; r < 4; ++r) {
        A_[r] = ABG[0][g*4 + r]; B_[r] = ABG[1][g*4 + r]; G_[r] = ABG[2][g*4 + r];
    }
    f32x4 acco[4];
    for (int et = 0; et < 4; ++et) acco[et] = (f32x4){0.f,0.f,0.f,0.f};

    int jtmax = t >> 2;
    for (int jt = wv; jt <= jtmax; jt += 4) {
        int j0 = jt*64;
        for (int ct = 0; ct < 4; ++ct) {
            const short* krow = (const short*)Kb + ((size_t)h*SEQ + j0 + ct*16 + n)*HD + g*8;
            bf16x8 kb0 = *(const bf16x8*)krow;
            bf16x8 kb1 = *(const bf16x8*)(krow + 32);
            f32x4 sacc = {0.f,0.f,0.f,0.f};
            sacc = __builtin_amdgcn_mfma_f32_16x16x32_bf16(qa0, kb0, sacc, 0, 0, 0);
            sacc = __builtin_amdgcn_mfma_f32_16x16x32_bf16(qa1, kb1, sacc, 0, 0, 0);
            int j = j0 + ct*16 + n;
            float sj = si[j];
            float ej = expf(sj - sm);
            int chunk = ct*2 + (n>>3), e = n&7;
            for (int r = 0; r < 4; ++r) {
                int m = m0 + g*4 + r;
                float w = (j <= m) ? (A_[r]*ej + B_[r]*sj + G_[r]) : 0.f;
                int ml = g*4 + r;
                Pw[ml*64 + (chunk ^ (ml&7))*8 + e] = f2bs(w * sacc[r]);
            }
        }
        const short* vb = (const short*)Vt + (size_t)h*HD*SEQ;
        for (int et = 0; et < 4; ++et) {
            for (int sub = 0; sub < 2; ++sub) {
                int q = sub*4 + g;
                bf16x8 pa = *(const bf16x8*)(&Pw[n*64 + (q ^ (n&7))*8]);
                bf16x8 vfr = *(const bf16x8*)(vb + (size_t)(et*16 + n)*SEQ + j0 + sub*32 + g*8);
                acco[et] = __builtin_amdgcn_mfma_f32_16x16x32_bf16(pa, vfr, acco[et], 0, 0, 0);
            }
        }
    }
    for (int et = 0; et < 4; ++et)
        for (int r = 0; r < 4; ++r)
            Op[wv][g*4 + r][et*16 + n] = acco[et][r];
    __syncthreads();
    for (int rr = 0; rr < 4; ++rr) {
        int row = wv*4 + rr;
        float v = Op[0][row][lane] + Op[1][row][lane] + Op[2][row][lane] + Op[3][row][lane];
        float sm2 = wave_reduce_sum(v);
        float sq = wave_reduce_sum(v*v);
        float mu = sm2 * (1.f/64.f);
        float var = fmaxf(sq * (1.f/64.f) - mu*mu, 0.f);
        float invs = rsqrtf(var + 1e-5f);
        opre[(size_t)(m0 + row)*DIM + h*HD + lane] = __float2bfloat16((v - mu) * invs);
    }
}

// ---------------- K5: output projection, 64x64 dbuf GEMM, DMA staging, f32 out -
__global__ __launch_bounds__(256, 4) void k_oproj(const short* __restrict__ A,
    const short* __restrict__ Wob, float* __restrict__ out)
{
    int rt = blockIdx.x, ct = blockIdx.y;
    __shared__ short lds[16384];   // A dbuf @0/4096, B dbuf @8192/12288 (64x64)

    int tid = threadIdx.x;
    int wv = tid>>6, lane = tid&63, g = lane>>4, n = lane&15;
    int wm = wv>>1, wn = wv&1;

    auto dma_step = [&](int buf, int k0) {
        short* Ab = lds + buf*4096;
        short* Bb = lds + 8192 + buf*4096;
        for (int p = 0; p < 2; ++p) {
            int sbase = p*256 + wv*64;
            int s = sbase + lane;
            int r = s >> 3, c = s & 7, cl = c ^ (r & 7);
            async_copy16(A + (size_t)(rt*64 + r)*DIM + k0 + cl*8, Ab + sbase*8, lane);
            async_copy16(Wob + (size_t)(ct*64 + r)*DIM + k0 + cl*8, Bb + sbase*8, lane);
        }
    };

    f32x4 acc[2][2];
    for (int i=0;i<2;++i) for (int j=0;j<2;++j) acc[i][j] = (f32x4){0,0,0,0};

    dma_step(0, 0);
    for (int it = 0; it < 12; ++it) {
        __syncthreads();
        if (it < 11) dma_step(1 - (it & 1), (it + 1)*64);
        int buf = it & 1;
        const short* Ab = lds + buf*4096;
        const short* Bb = lds + 8192 + buf*4096;
        for (int ks = 0; ks < 2; ++ks) {
            int q = ks*4 + g;
            bf16x8 af[2], bfr[2];
            for (int i=0;i<2;++i)
                af[i] = *(const bf16x8*)(&Ab[((wm*32+i*16+n)*8 + (q ^ (n&7)))*8]);
            for (int j=0;j<2;++j)
                bfr[j] = *(const bf16x8*)(&Bb[((wn*32+j*16+n)*8 + (q ^ (n&7)))*8]);
            for (int i=0;i<2;++i)
                for (int j=0;j<2;++j)
                    acc[i][j] = __builtin_amdgcn_mfma_f32_16x16x32_bf16(af[i], bfr[j], acc[i][j], 0,0,0);
        }
    }
    for (int i=0;i<2;++i) for (int j=0;j<2;++j) for (int r=0;r<4;++r) {
        int row = rt*64 + wm*32 + i*16 + g*4 + r;
        int col = ct*64 + wn*32 + j*16 + n;
        out[(size_t)row*DIM + col] = acc[i][j][r];
    }
}

extern "C" void kernel_launch(void* const* d_in, const int* in_sizes, int n_in,
                              void* d_out, int out_size, void* d_ws, size_t ws_size,
                              hipStream_t stream) {
    const float* X   = (const float*)d_in[0];
    const float* Wq  = (const float*)d_in[1];
    const float* Wk  = (const float*)d_in[2];
    const float* Wv  = (const float*)d_in[3];
    const float* Wu  = (const float*)d_in[4];
    const float* Wg  = (const float*)d_in[5];
    const float* Wo  = (const float*)d_in[6];
    const float* pmu = (const float*)d_in[7];
    const float* plt = (const float*)d_in[8];

    char* w = (char*)d_ws;
    __hip_bfloat16* Qb   = (__hip_bfloat16*)(w + 0);
    __hip_bfloat16* Kb   = (__hip_bfloat16*)(w + 1572864);
    __hip_bfloat16* Vt   = (__hip_bfloat16*)(w + 3145728);
    __hip_bfloat16* opre = (__hip_bfloat16*)(w + 4718592);
    float*          G    = (float*)(w + 6291456);
    float*          si_  = (float*)(w + 6438912);
    short*          Xb   = (short*)(w + 6684672);
    short*          Wqb  = (short*)(w + 8257536);
    short*          Wkb  = (short*)(w + 9437184);
    short*          Wvb  = (short*)(w + 10616832);
    short*          Wgb  = (short*)(w + 12976128);
    short*          Wob  = (short*)(w + 13031424);
    __hip_bfloat16* Ub   = (__hip_bfloat16*)d_out;   // scratch; k_oproj overwrites last
    float*          out  = (float*)d_out;

    hipLaunchKernelGGL(k_prep, dim3(384, 7), dim3(256), 0, stream,
                       X, Wq, Wk, Wv, Wg, Wo, Wu, Xb, Wqb, Wkb, Wvb, Wgb, Wob, Ub);
    hipLaunchKernelGGL(k_projsi, dim3(1360), dim3(256), 0, stream,
                       Xb, Wqb, Wkb, Wvb, Wgb, Ub, pmu, plt, Qb, Kb, Vt, G, si_);
    hipLaunchKernelGGL(k_attn, dim3(64, NH), dim3(256), 0, stream,
                       Qb, Kb, Vt, si_, G, opre);
    hipLaunchKernelGGL(k_oproj, dim3(16, 12), dim3(256), 0, stream,
                       (const short*)opre, Wob, out);
}

// Round 10
// 142.770 us; speedup vs baseline: 1.0398x; 1.0398x over previous
//
#include <hip/hip_runtime.h>
#include <hip/hip_bf16.h>
#include <math.h>

typedef __attribute__((ext_vector_type(8))) short bf16x8;
typedef __attribute__((ext_vector_type(4))) float f32x4;

#define SEQ 1024
#define DIM 768
#define NH 12
#define HD 64

// ws layout (BYTE offsets):
//   Qb   bf16 [12][1024][64]  @ 0
//   Kb   bf16 [12][1024][64]  @ 1572864
//   Vt   bf16 [768][1024]     @ 3145728   (v transposed: [h*64+e][l])
//   opre bf16 [1024][768]     @ 4718592
//   G    f32  [1024][36]      @ 6291456
//   si   f32  [12][1024]      @ 6438912
//   Xb   bf16 [1024][768]     @ 6684672   (pre-cast inputs for DMA staging)
//   Wqb  bf16 [768][768]      @ 8257536
//   Wkb  bf16 [768][768]      @ 9437184
//   Wvb  bf16 [768][768]      @ 10616832
//   Wub  bf16 [768][768]      @ 11796480
//   Wgb  bf16 [36][768]       @ 12976128
//   Wob  bf16 [768][768]      @ 13031424
// u (bf16 [12][1024][64]) borrows d_out as scratch; k_oproj overwrites it last.
// NOTE (R9): grid.sync() costs ~50 µs on MI355X — never fuse via cooperative.
// R12/R14: failed scan merges — latency lever = serial iters/wave x concurrency.
// R13: f32 reg-staging costs ~+10 µs vs bf16-precast DMA.
// R15: k_si j-split across waves. R16: proj5 64x64 re-tile (784 blocks).
// R17: scan folded into attn (block-local max; zero serialization). 144.5 µs.
// R19 post-mortem (+4 µs, REVERTED): bundled u-GEMM-into-prep (f32 staging on
// prep's critical path) with si-into-proj (requires the former -> race
// otherwise). Boundary cost is ~5 µs, not 10-15: no remaining merge pays.
// R20: single change vs R8 — k_oproj 64x64 -> 32x64 tiles (192 -> 384 blocks,
// 0.75 -> 1.5 blocks/CU; same under-occupancy diagnosis that paid in R16).

__device__ __forceinline__ float wave_reduce_sum(float v) {
    for (int off = 1; off < 64; off <<= 1) v += __shfl_xor(v, off);
    return v;
}
__device__ __forceinline__ short f2bs(float x) {
    __hip_bfloat16 h = __float2bfloat16(x);
    return *reinterpret_cast<short*>(&h);
}
__device__ __forceinline__ float bs2f(short x) {
    __hip_bfloat16 h = *reinterpret_cast<__hip_bfloat16*>(&x);
    return (float)h;
}
__device__ __forceinline__ bf16x8 cvt8r(const float4& a, const float4& b) {
    bf16x8 r;
    r[0]=f2bs(a.x); r[1]=f2bs(a.y); r[2]=f2bs(a.z); r[3]=f2bs(a.w);
    r[4]=f2bs(b.x); r[5]=f2bs(b.y); r[6]=f2bs(b.z); r[7]=f2bs(b.w);
    return r;
}
__device__ __forceinline__ void async_copy16(const void* gptr, void* ldsbase, int lane) {
#if __has_builtin(__builtin_amdgcn_global_load_lds)
    __builtin_amdgcn_global_load_lds(
        (const __attribute__((address_space(1))) unsigned int*)gptr,
        (__attribute__((address_space(3))) unsigned int*)ldsbase, 16, 0, 0);
#else
    *(bf16x8*)((short*)ldsbase + lane*8) = *(const bf16x8*)gptr;
#endif
}

// ---------------- K0: pre-cast X + weights to bf16 (one pass, BW-bound) -------
__global__ __launch_bounds__(256) void k_prep(const float* __restrict__ X,
    const float* __restrict__ Wq, const float* __restrict__ Wk,
    const float* __restrict__ Wv, const float* __restrict__ Wu,
    const float* __restrict__ Wg, const float* __restrict__ Wo,
    short* __restrict__ Xb, short* __restrict__ Wqb, short* __restrict__ Wkb,
    short* __restrict__ Wvb, short* __restrict__ Wub, short* __restrict__ Wgb,
    short* __restrict__ Wob)
{
    int seg = blockIdx.y;
    const float* src; short* dst; int n8;
    switch (seg) {
        case 0: src = X;  dst = Xb;  n8 = 98304; break;
        case 1: src = Wq; dst = Wqb; n8 = 73728; break;
        case 2: src = Wk; dst = Wkb; n8 = 73728; break;
        case 3: src = Wv; dst = Wvb; n8 = 73728; break;
        case 4: src = Wu; dst = Wub; n8 = 73728; break;
        case 5: src = Wg; dst = Wgb; n8 = 3456;  break;
        default: src = Wo; dst = Wob; n8 = 73728; break;
    }
    int i = blockIdx.x*256 + threadIdx.x;
    if (i >= n8) return;
    const float* s = src + (size_t)i*8;
    *(bf16x8*)(dst + (size_t)i*8) = cvt8r(*(const float4*)s, *(const float4*)(s + 4));
}

// ---------------- K1: 5 projections, 64x64 dbuf GEMM, 784 blocks -------------
// t < 576: q/k/u (192 each: rt 0..15 x ct 0..11, head = ct)
// t in [576,768): v, A/B swapped (A=Wv rows -> Vt rows, B=X rows -> cols)
// t >= 768: gate (16 blocks, cols clamped to 36)
__global__ __launch_bounds__(256, 4) void k_proj5(const short* __restrict__ Xb,
    const short* __restrict__ Wqb, const short* __restrict__ Wkb,
    const short* __restrict__ Wvb, const short* __restrict__ Wub,
    const short* __restrict__ Wgb,
    __hip_bfloat16* __restrict__ Qb, __hip_bfloat16* __restrict__ Kb,
    __hip_bfloat16* __restrict__ Vt, __hip_bfloat16* __restrict__ Ub,
    float* __restrict__ G)
{
    int t = blockIdx.x;
    int mat, rt, ct;
    if (t < 576)      { int m3 = t/192; mat = (m3==2)?3:m3; int r = t%192; rt = r/12; ct = r%12; }
    else if (t < 768) { mat = 2; int r = t-576; rt = r/16; ct = r%16; }
    else              { mat = 4; rt = t-768; ct = 0; }

    __shared__ short lds[16384];   // A dbuf @0/4096, B dbuf @8192/12288 (64x64)

    int tid = threadIdx.x;
    int wv = tid>>6, lane = tid&63, g = lane>>4, n = lane&15;
    int wm = wv>>1, wn = wv&1;

    const short* Asrc; const short* Bsrc; int arow0, brow0, Brows;
    if (mat == 2) { Asrc = Wvb; Bsrc = Xb; arow0 = rt*64; brow0 = ct*64; Brows = SEQ; }
    else {
        Asrc = Xb; arow0 = rt*64; brow0 = ct*64;
        Bsrc = (mat==0)?Wqb:(mat==1)?Wkb:(mat==3)?Wub:Wgb;
        Brows = (mat==4) ? 36 : DIM;
    }

    auto dma_step = [&](int buf, int k0) {
        short* Ab = lds + buf*4096;
        short* Bb = lds + 8192 + buf*4096;
        for (int p = 0; p < 2; ++p) {
            int sbase = p*256 + wv*64;
            int s = sbase + lane;
            int r = s >> 3, c = s & 7, cl = c ^ (r & 7);
            async_copy16(Asrc + (size_t)(arow0 + r)*DIM + k0 + cl*8, Ab + sbase*8, lane);
            int gr = brow0 + r; if (gr >= Brows) gr = Brows - 1;   // gate clamp
            async_copy16(Bsrc + (size_t)gr*DIM + k0 + cl*8, Bb + sbase*8, lane);
        }
    };

    f32x4 acc[2][2];
    for (int i=0;i<2;++i) for (int j=0;j<2;++j) acc[i][j] = (f32x4){0,0,0,0};

    dma_step(0, 0);
    for (int it = 0; it < 12; ++it) {
        __syncthreads();                                // drains DMA for buf it&1
        if (it < 11) dma_step(1 - (it & 1), (it + 1)*64);
        int buf = it & 1;
        const short* Ab = lds + buf*4096;
        const short* Bb = lds + 8192 + buf*4096;
        for (int ks = 0; ks < 2; ++ks) {
            int q = ks*4 + g;
            bf16x8 af[2], bfr[2];
            for (int i=0;i<2;++i)
                af[i] = *(const bf16x8*)(&Ab[((wm*32+i*16+n)*8 + (q ^ (n&7)))*8]);
            for (int j=0;j<2;++j)
                bfr[j] = *(const bf16x8*)(&Bb[((wn*32+j*16+n)*8 + (q ^ (n&7)))*8]);
            for (int i=0;i<2;++i)
                for (int j=0;j<2;++j)
                    acc[i][j] = __builtin_amdgcn_mfma_f32_16x16x32_bf16(af[i], bfr[j], acc[i][j], 0,0,0);
        }
    }
    __syncthreads();

    // ---- gate: tiny, direct f32 writes (cols >= 36 masked) ----
    if (mat == 4) {
        for (int i=0;i<2;++i) for (int j=0;j<2;++j) for (int r=0;r<4;++r) {
            int row = rt*64 + wm*32 + i*16 + g*4 + r;
            int col = wn*32 + j*16 + n;
            if (col < 36) G[(size_t)row*36 + col] = acc[i][j][r];
        }
        return;
    }

    // ---- stage C tile bf16 [64 rows][64 cols] in LDS (reuses A0 buffer) ----
    short* C = lds;
    for (int i=0;i<2;++i) for (int j=0;j<2;++j) for (int r=0;r<4;++r)
        C[(wm*32 + i*16 + g*4 + r)*64 + wn*32 + j*16 + n] = f2bs(acc[i][j][r]);
    __syncthreads();

    if (mat == 2) {
        // C[e_local][l_local] -> Vt[rt*64+e][ct*64+l], 128B runs via uint
        const unsigned int* Cu = (const unsigned int*)C;
        for (int k = 0; k < 8; ++k) {
            int idx = k*256 + tid;           // 0..2047
            int row = idx >> 5, cu = idx & 31;
            ((unsigned int*)(Vt + (size_t)(rt*64 + row)*SEQ + ct*64))[cu] = Cu[row*32 + cu];
        }
    } else if (mat == 3) {
        // C[l_local][e] -> Ub[head=ct][rt*64+l][e], 128B rows via uint
        const unsigned int* Cu = (const unsigned int*)C;
        for (int k = 0; k < 8; ++k) {
            int idx = k*256 + tid;
            int row = idx >> 5, cu = idx & 31;
            ((unsigned int*)(Ub + ((size_t)ct*SEQ + rt*64 + row)*HD))[cu] = Cu[row*32 + cu];
        }
    } else {
        // q/k: fused RoPE (rotation recurrence) + L2 normalize, head = ct.
        __hip_bfloat16* dst = (mat==0) ? Qb : Kb;
        int i2 = lane >> 1;
        float inv = expf((float)i2 * (-9.210340371976184f / 32.f));  // 10000^{-i2/32}
        float c0, s0, C1, S1;
        sincosf((float)(rt*64 + wv*16) * inv, &s0, &c0);
        sincosf(inv, &S1, &C1);
        for (int k = 0; k < 16; ++k) {
            int row = wv*16 + k;
            int l = rt*64 + row;
            float x = bs2f(C[row*64 + lane]);
            float p = __shfl(x, lane ^ 32);
            float rot = (lane < 32) ? -p : p;
            float y = x*c0 + rot*s0;
            float nrm = wave_reduce_sum(y*y);
            y = y / fmaxf(sqrtf(nrm), 1e-12f);
            dst[((size_t)ct*SEQ + l)*HD + lane] = __float2bfloat16(y);
            float cn = c0*C1 - s0*S1;
            s0 = s0*C1 + c0*S1;
            c0 = cn;
        }
    }
}

// ---------------- K2: s_i via MFMA causal Gram rowsum, j-split across waves --
// Block (T,h): ONE 16-row tile; 4 waves stride the j-tile loop -> <=16 serial
// iters/wave; 768 blocks of TLP. Partial p[4] reduced via LDS. (R15)
__global__ __launch_bounds__(256) void k_si(const __hip_bfloat16* __restrict__ Ub,
    const float* __restrict__ pmu, const float* __restrict__ plt,
    float* __restrict__ si_)
{
    int T = blockIdx.x, h = blockIdx.y;   // T: 16-row tile 0..63
    int wv = threadIdx.x >> 6, lane = threadIdx.x & 63;
    int g = lane >> 4, n = lane & 15;
    int lbase = T*16;
    const short* ub = (const short*)Ub + (size_t)h*SEQ*HD;
    __shared__ float pbuf[4][16];

    bf16x8 a0 = *(const bf16x8*)(ub + (size_t)(lbase + n)*HD + g*8);
    bf16x8 a1 = *(const bf16x8*)(ub + (size_t)(lbase + n)*HD + 32 + g*8);

    float p[4] = {0.f, 0.f, 0.f, 0.f};

    for (int jt = wv; jt < T; jt += 4) {   // strictly-below tiles: unmasked
        const short* br = ub + (size_t)(jt*16 + n)*HD + g*8;
        bf16x8 b0 = *(const bf16x8*)br;
        bf16x8 b1 = *(const bf16x8*)(br + 32);
        f32x4 sacc = {0.f,0.f,0.f,0.f};
        sacc = __builtin_amdgcn_mfma_f32_16x16x32_bf16(a0, b0, sacc, 0,0,0);
        sacc = __builtin_amdgcn_mfma_f32_16x16x32_bf16(a1, b1, sacc, 0,0,0);
        for (int r = 0; r < 4; ++r) p[r] += sacc[r];
    }
    if (wv == 0) {                         // diagonal tile: mask j<=l (n <= g*4+r)
        const short* br = ub + (size_t)(lbase + n)*HD + g*8;
        bf16x8 b0 = *(const bf16x8*)br;
        bf16x8 b1 = *(const bf16x8*)(br + 32);
        f32x4 d = {0.f,0.f,0.f,0.f};
        d = __builtin_amdgcn_mfma_f32_16x16x32_bf16(a0, b0, d, 0,0,0);
        d = __builtin_amdgcn_mfma_f32_16x16x32_bf16(a1, b1, d, 0,0,0);
        for (int r = 0; r < 4; ++r) if (n <= g*4 + r) p[r] += d[r];
    }
    if (wv == 1) {                         // prior-mu term (partial over cols n+16c)
        float ltau = expf(fminf(fmaxf(plt[h], -50.f), 30.f));
        for (int r = 0; r < 4; ++r) {
            int l = lbase + g*4 + r;
            float acc = 0.f;
            for (int c = n; c < 64; c += 16)
                acc += bs2f(ub[(size_t)l*HD + c]) * pmu[h*HD + c];
            p[r] += ltau * acc;
        }
    }
    for (int off = 1; off < 16; off <<= 1)  // reduce over the 16 j-columns
        for (int r = 0; r < 4; ++r) p[r] += __shfl_xor(p[r], off);
    if (n == 0)
        for (int r = 0; r < 4; ++r) pbuf[wv][g*4 + r] = p[r];
    __syncthreads();
    if (wv == 0 && n == 0) {
        float ltau = expf(fminf(fmaxf(plt[h], -50.f), 30.f));
        for (int r = 0; r < 4; ++r) {
            int row = g*4 + r, l = lbase + row;
            float tot = pbuf[0][row] + pbuf[1][row] + pbuf[2][row] + pbuf[3][row];
            si_[h*SEQ + l] = -tot * 0.125f / (ltau + (float)(l + 1));
        }
    }
}

// ---------------- K4: attn + inline per-block scan + LayerNorm ---------------
// R17: alpha/beta/gamma computed in-block from si with a BLOCK-LOCAL max.
__global__ __launch_bounds__(256) void k_attn(const __hip_bfloat16* __restrict__ Qb,
    const __hip_bfloat16* __restrict__ Kb, const __hip_bfloat16* __restrict__ Vt,
    const float* __restrict__ si_, const float* __restrict__ Gm,
    __hip_bfloat16* __restrict__ opre)
{
    int t = blockIdx.x, h = blockIdx.y;   // q-tile 0..63
    int tid = threadIdx.x;
    int wv = tid >> 6, lane = tid & 63;
    int g = lane >> 4, n = lane & 15;
    __shared__ short P[4][16*64];
    __shared__ float Op[4][16][64];
    __shared__ float red[4][2];
    __shared__ float ABG[3][16];
    __shared__ float smax_s;
    short* Pw = P[wv];
    int m0 = t*16;
    const float* si = si_ + h*SEQ;

    const short* qrow = (const short*)Qb + ((size_t)h*SEQ + m0 + n)*HD + g*8;
    bf16x8 qa0 = *(const bf16x8*)qrow;
    bf16x8 qa1 = *(const bf16x8*)(qrow + 32);

    // Phase A: block-local max over si[0 .. m0+16)
    float mx = -1e30f;
    for (int j = tid; j < m0 + 16; j += 256) mx = fmaxf(mx, si[j]);
    for (int off = 1; off < 64; off <<= 1) mx = fmaxf(mx, __shfl_xor(mx, off));
    if (lane == 0) red[wv][0] = mx;
    __syncthreads();
    if (tid == 0) smax_s = fmaxf(fmaxf(red[0][0], red[1][0]), fmaxf(red[2][0], red[3][0]));
    __syncthreads();
    float sm = smax_s;

    // Phase B: E_base/P_base = sums over j < m0
    float se = 0.f, ss = 0.f;
    for (int j = tid; j < m0; j += 256) { float s = si[j]; se += expf(s - sm); ss += s; }
    se = wave_reduce_sum(se); ss = wave_reduce_sum(ss);
    __syncthreads();                       // red[][] reuse
    if (lane == 0) { red[wv][0] = se; red[wv][1] = ss; }
    __syncthreads();

    // Phase C: wave 0 lanes 0..15 -> per-row alpha/beta/gamma
    if (wv == 0 && lane < 16) {
        float Eb = red[0][0] + red[1][0] + red[2][0] + red[3][0];
        float Pb = red[0][1] + red[1][1] + red[2][1] + red[3][1];
        float sv = si[m0 + lane];
        float pe = expf(sv - sm), ps = sv;
        for (int off = 1; off < 16; off <<= 1) {
            float t1 = __shfl_up(pe, off), t2 = __shfl_up(ps, off);
            if (lane >= off) { pe += t1; ps += t2; }
        }
        float E = Eb + pe, Pv = Pb + ps;   // inclusive prefixes at row m0+lane
        float tv = (float)(m0 + lane + 1);
        float s1 = 1.f / (1.f + expf(-Gm[(size_t)(m0 + lane)*36 + h*3 + 0]));
        float sh = 1.f / (1.f + expf(-Gm[(size_t)(m0 + lane)*36 + h*3 + 1]));
        float a = sh / (E + 1e-12f);
        float b = (s1 - sh) / tv;
        ABG[0][lane] = a;
        ABG[1][lane] = b;
        ABG[2][lane] = -((b * Pv + sh) / tv);
    }
    __syncthreads();

    float A_[4], B_[4], G_[4];
    for (int r = 0; r < 4; ++r) {
        A_[r] = ABG[0][g*4 + r]; B_[r] = ABG[1][g*4 + r]; G_[r] = ABG[2][g*4 + r];
    }
    f32x4 acco[4];
    for (int et = 0; et < 4; ++et) acco[et] = (f32x4){0.f,0.f,0.f,0.f};

    int jtmax = t >> 2;
    for (int jt = wv; jt <= jtmax; jt += 4) {
        int j0 = jt*64;
        for (int ct = 0; ct < 4; ++ct) {
            const short* krow = (const short*)Kb + ((size_t)h*SEQ + j0 + ct*16 + n)*HD + g*8;
            bf16x8 kb0 = *(const bf16x8*)krow;
            bf16x8 kb1 = *(const bf16x8*)(krow + 32);
            f32x4 sacc = {0.f,0.f,0.f,0.f};
            sacc = __builtin_amdgcn_mfma_f32_16x16x32_bf16(qa0, kb0, sacc, 0, 0, 0);
            sacc = __builtin_amdgcn_mfma_f32_16x16x32_bf16(qa1, kb1, sacc, 0, 0, 0);
            int j = j0 + ct*16 + n;
            float sj = si[j];
            float ej = expf(sj - sm);
            int chunk = ct*2 + (n>>3), e = n&7;
            for (int r = 0; r < 4; ++r) {
                int m = m0 + g*4 + r;
                float w = (j <= m) ? (A_[r]*ej + B_[r]*sj + G_[r]) : 0.f;
                int ml = g*4 + r;
                Pw[ml*64 + (chunk ^ (ml&7))*8 + e] = f2bs(w * sacc[r]);
            }
        }
        const short* vb = (const short*)Vt + (size_t)h*HD*SEQ;
        for (int et = 0; et < 4; ++et) {
            for (int sub = 0; sub < 2; ++sub) {
                int q = sub*4 + g;
                bf16x8 pa = *(const bf16x8*)(&Pw[n*64 + (q ^ (n&7))*8]);
                bf16x8 vfr = *(const bf16x8*)(vb + (size_t)(et*16 + n)*SEQ + j0 + sub*32 + g*8);
                acco[et] = __builtin_amdgcn_mfma_f32_16x16x32_bf16(pa, vfr, acco[et], 0, 0, 0);
            }
        }
    }
    for (int et = 0; et < 4; ++et)
        for (int r = 0; r < 4; ++r)
            Op[wv][g*4 + r][et*16 + n] = acco[et][r];
    __syncthreads();
    for (int rr = 0; rr < 4; ++rr) {
        int row = wv*4 + rr;
        float v = Op[0][row][lane] + Op[1][row][lane] + Op[2][row][lane] + Op[3][row][lane];
        float sm2 = wave_reduce_sum(v);
        float sq = wave_reduce_sum(v*v);
        float mu = sm2 * (1.f/64.f);
        float var = fmaxf(sq * (1.f/64.f) - mu*mu, 0.f);
        float invs = rsqrtf(var + 1e-5f);
        opre[(size_t)(m0 + row)*DIM + h*HD + lane] = __float2bfloat16((v - mu) * invs);
    }
}

// ---------------- K5: output projection, 32x64 dbuf GEMM, 384 blocks ---------
// R20: tile 64x64 -> 32x64 (grid 32x12, 1.5 blocks/CU). Wave (wm,wn) owns a
// 16x32 sub-tile: acc[1][2]. A-stage: 1 chunk/thread; B: 2. LDS 24 KB (256,4).
__global__ __launch_bounds__(256, 4) void k_oproj(const short* __restrict__ A,
    const short* __restrict__ Wob, float* __restrict__ out)
{
    int rt = blockIdx.x, ct = blockIdx.y;
    __shared__ short lds[12288];   // A dbuf @0/2048 (32x64), B dbuf @4096/8192 (64x64)

    int tid = threadIdx.x;
    int wv = tid>>6, lane = tid&63, g = lane>>4, n = lane&15;
    int wm = wv>>1, wn = wv&1;

    auto dma_step = [&](int buf, int k0) {
        short* Ab = lds + buf*2048;
        short* Bb = lds + 4096 + buf*4096;
        {   // A: 32 rows x 8 chunks = 256 slots, 1 per thread
            int s = wv*64 + lane;
            int r = s >> 3, c = s & 7, cl = c ^ (r & 7);
            async_copy16(A + (size_t)(rt*32 + r)*DIM + k0 + cl*8, Ab + (s & ~63)*8, lane);
        }
        for (int p = 0; p < 2; ++p) {       // B: 64 rows x 8 chunks
            int sbase = p*256 + wv*64;
            int s = sbase + lane;
            int r = s >> 3, c = s & 7, cl = c ^ (r & 7);
            async_copy16(Wob + (size_t)(ct*64 + r)*DIM + k0 + cl*8, Bb + sbase*8, lane);
        }
    };

    f32x4 acc[2];
    for (int j=0;j<2;++j) acc[j] = (f32x4){0,0,0,0};

    dma_step(0, 0);
    for (int it = 0; it < 12; ++it) {
        __syncthreads();
        if (it < 11) dma_step(1 - (it & 1), (it + 1)*64);
        int buf = it & 1;
        const short* Ab = lds + buf*2048;
        const short* Bb = lds + 4096 + buf*4096;
        for (int ks = 0; ks < 2; ++ks) {
            int q = ks*4 + g;
            bf16x8 af = *(const bf16x8*)(&Ab[((wm*16+n)*8 + (q ^ (n&7)))*8]);
            bf16x8 bfr[2];
            for (int j=0;j<2;++j)
                bfr[j] = *(const bf16x8*)(&Bb[((wn*32+j*16+n)*8 + (q ^ (n&7)))*8]);
            for (int j=0;j<2;++j)
                acc[j] = __builtin_amdgcn_mfma_f32_16x16x32_bf16(af, bfr[j], acc[j], 0,0,0);
        }
    }
    for (int j=0;j<2;++j) for (int r=0;r<4;++r) {
        int row = rt*32 + wm*16 + g*4 + r;
        int col = ct*64 + wn*32 + j*16 + n;
        out[(size_t)row*DIM + col] = acc[j][r];
    }
}

extern "C" void kernel_launch(void* const* d_in, const int* in_sizes, int n_in,
                              void* d_out, int out_size, void* d_ws, size_t ws_size,
                              hipStream_t stream) {
    const float* X   = (const float*)d_in[0];
    const float* Wq  = (const float*)d_in[1];
    const float* Wk  = (const float*)d_in[2];
    const float* Wv  = (const float*)d_in[3];
    const float* Wu  = (const float*)d_in[4];
    const float* Wg  = (const float*)d_in[5];
    const float* Wo  = (const float*)d_in[6];
    const float* pmu = (const float*)d_in[7];
    const float* plt = (const float*)d_in[8];

    char* w = (char*)d_ws;
    __hip_bfloat16* Qb   = (__hip_bfloat16*)(w + 0);
    __hip_bfloat16* Kb   = (__hip_bfloat16*)(w + 1572864);
    __hip_bfloat16* Vt   = (__hip_bfloat16*)(w + 3145728);
    __hip_bfloat16* opre = (__hip_bfloat16*)(w + 4718592);
    float*          G    = (float*)(w + 6291456);
    float*          si_  = (float*)(w + 6438912);
    short*          Xb   = (short*)(w + 6684672);
    short*          Wqb  = (short*)(w + 8257536);
    short*          Wkb  = (short*)(w + 9437184);
    short*          Wvb  = (short*)(w + 10616832);
    short*          Wub  = (short*)(w + 11796480);
    short*          Wgb  = (short*)(w + 12976128);
    short*          Wob  = (short*)(w + 13031424);
    __hip_bfloat16* Ub   = (__hip_bfloat16*)d_out;   // scratch; k_oproj overwrites last
    float*          out  = (float*)d_out;

    hipLaunchKernelGGL(k_prep, dim3(384, 7), dim3(256), 0, stream,
                       X, Wq, Wk, Wv, Wu, Wg, Wo, Xb, Wqb, Wkb, Wvb, Wub, Wgb, Wob);
    hipLaunchKernelGGL(k_proj5, dim3(784), dim3(256), 0, stream,
                       Xb, Wqb, Wkb, Wvb, Wub, Wgb, Qb, Kb, Vt, Ub, G);
    hipLaunchKernelGGL(k_si, dim3(64, NH), dim3(256), 0, stream,
                       Ub, pmu, plt, si_);
    hipLaunchKernelGGL(k_attn, dim3(64, NH), dim3(256), 0, stream,
                       Qb, Kb, Vt, si_, G, opre);
    hipLaunchKernelGGL(k_oproj, dim3(32, 12), dim3(256), 0, stream,
                       (const short*)opre, Wob, out);
}